// Round 10
// baseline (324.960 us; speedup 1.0000x reference)
//
#include <hip/hip_runtime.h>
#include <hip/hip_bf16.h>
#include <hip/hip_cooperative_groups.h>

namespace cg = cooperative_groups;

// Problem constants
#define B 64
#define D 1024
#define H 1024
#define C 32           // chunks along D
#define L (D / C)      // chunk length = 32
#define BG 4           // batch rows per work item
#define NBG (B / BG)   // 16 batch groups
#define HQ 4           // h-quarters
#define HP (H / HQ)    // 256 h per item = 1 h per thread
#define MAXGRID 1024

// DPP quad-perm cross-lane (VALU-speed, no LDS)
__device__ __forceinline__ float dpp_xor1(float v) {
    int i = __builtin_bit_cast(int, v);
    i = __builtin_amdgcn_mov_dpp(i, 0xB1, 0xF, 0xF, true);  // quad_perm [1,0,3,2]
    return __builtin_bit_cast(float, i);
}
__device__ __forceinline__ float dpp_xor2(float v) {
    int i = __builtin_bit_cast(int, v);
    i = __builtin_amdgcn_mov_dpp(i, 0x4E, 0xF, 0xF, true);  // quad_perm [2,3,0,1]
    return __builtin_bit_cast(float, i);
}

// ===========================================================================
// Cooperative single-kernel path (grid-stride phases, runtime grid size)
// ===========================================================================
__global__ void __launch_bounds__(256)
k_fused(const float* __restrict__ x,
        const float* __restrict__ in_W,
        const float* __restrict__ in_b,
        const float* __restrict__ h_W,
        const float* __restrict__ h_b,
        float* __restrict__ Wt,   // [D, H]      4 MB ws
        float* __restrict__ S,    // [B, C, H]   8 MB ws
        float* __restrict__ Q,    // [HQ, B, D]  1 MB ws
        float* __restrict__ out,
        int ngrid) {
    cg::grid_group grid = cg::this_grid();
    int bid = blockIdx.x;
    int tid = threadIdx.x;

    __shared__ float tile[32][33];
    __shared__ float4 xs4[L];
    __shared__ float red[4][BG][L];

    // ---------------- Phase 0: transpose in_W -> Wt (1024 tile items) -------
    for (int t = bid; t < 1024; t += ngrid) {
        int bx = (t & 31) * 32;   // d-range
        int by = (t >> 5) * 32;   // h-range
        int tx = tid & 31;
        int ty = tid >> 5;        // 0..7
        __syncthreads();          // protect tile reuse across items
        #pragma unroll
        for (int r = 0; r < 32; r += 8)
            tile[ty + r][tx] = in_W[(size_t)(by + ty + r) * D + (bx + tx)];
        __syncthreads();
        #pragma unroll
        for (int r = 0; r < 32; r += 8)
            Wt[(size_t)(bx + ty + r) * H + (by + tx)] = tile[tx][ty + r];
    }
    grid.sync();

    // ---------------- Phase 1: chunk sums (2048 items) ----------------------
    for (int item = bid; item < 2048; item += ngrid) {
        int bg  = item >> 7;
        int chq = item & 127;
        int c   = chq >> 2;
        int hq  = chq & 3;
        int b0  = bg * BG;
        int h   = hq * HP + tid;

        __syncthreads();   // protect xs4 reuse across items
        if (tid < L) {
            int i = c * L + tid;
            xs4[tid] = make_float4(x[(size_t)b0 * D + i],
                                   x[(size_t)(b0 + 1) * D + i],
                                   x[(size_t)(b0 + 2) * D + i],
                                   x[(size_t)(b0 + 3) * D + i]);
        }
        __syncthreads();

        float acc0 = 0.f, acc1 = 0.f, acc2 = 0.f, acc3 = 0.f;
        #pragma unroll
        for (int j = 0; j < L; ++j) {
            float w = Wt[(size_t)(c * L + j) * H + h];
            float4 xf = xs4[j];
            acc0 = fmaf(xf.x, w, acc0);
            acc1 = fmaf(xf.y, w, acc1);
            acc2 = fmaf(xf.z, w, acc2);
            acc3 = fmaf(xf.w, w, acc3);
        }
        S[((size_t)b0 * C + c) * H + h]       = acc0;
        S[((size_t)(b0 + 1) * C + c) * H + h] = acc1;
        S[((size_t)(b0 + 2) * C + c) * H + h] = acc2;
        S[((size_t)(b0 + 3) * C + c) * H + h] = acc3;
    }
    grid.sync();

    // ---------------- Phase 2: main chain with fused prefix (2048 items) ----
    {
        int lane = tid & 63;
        int wv = tid >> 6;
        int ph = lane & 3;
        bool kk0 = (ph == 0), kk1 = (ph == 1), kk2 = (ph == 2), kk3 = (ph == 3);

        for (int item = bid; item < 2048; item += ngrid) {
            int c   = item >> 6;        // 0..31
            int r6  = item & 63;
            int bg  = r6 >> 2;          // 0..15
            int hq  = r6 & 3;           // 0..3
            int b0  = bg * BG;
            int h   = hq * HP + tid;

            __syncthreads();   // protect xs4/red reuse across items
            if (tid < L) {
                int i = c * L + tid;
                xs4[tid] = make_float4(x[(size_t)b0 * D + i],
                                       x[(size_t)(b0 + 1) * D + i],
                                       x[(size_t)(b0 + 2) * D + i],
                                       x[(size_t)(b0 + 3) * D + i]);
            }

            // fused exclusive prefix over chunks (coalesced, 4 chains)
            float ib = in_b[h];
            float a0 = ib, a1 = ib, a2 = ib, a3 = ib;
            #pragma unroll 4
            for (int cc = 0; cc < c; ++cc) {
                a0 += S[((size_t)b0 * C + cc) * H + h];
                a1 += S[((size_t)(b0 + 1) * C + cc) * H + h];
                a2 += S[((size_t)(b0 + 2) * C + cc) * H + h];
                a3 += S[((size_t)(b0 + 3) * C + cc) * H + h];
            }
            __syncthreads();

            float pr0[8], pr1[8], pr2[8], pr3[8];
            #pragma unroll
            for (int s = 0; s < 8; ++s) { pr0[s] = 0.f; pr1[s] = 0.f; pr2[s] = 0.f; pr3[s] = 0.f; }

            #pragma unroll
            for (int il = 0; il < L; ++il) {
                int i = c * L + il;
                float w   = h_W[(size_t)i * H + h];
                float wtv = Wt[(size_t)i * H + h];
                float4 xf = xs4[il];
                int s = il >> 2;
                bool keep = (il & 3) == 0 ? kk0 : ((il & 3) == 1 ? kk1 : ((il & 3) == 2 ? kk2 : kk3));

                float p0 = fmaxf(a0, 0.f) * w;
                float t0 = p0 + dpp_xor1(p0); t0 = t0 + dpp_xor2(t0);
                pr0[s] = keep ? t0 : pr0[s];
                a0 = fmaf(xf.x, wtv, a0);

                float p1 = fmaxf(a1, 0.f) * w;
                float t1 = p1 + dpp_xor1(p1); t1 = t1 + dpp_xor2(t1);
                pr1[s] = keep ? t1 : pr1[s];
                a1 = fmaf(xf.y, wtv, a1);

                float p2 = fmaxf(a2, 0.f) * w;
                float t2 = p2 + dpp_xor1(p2); t2 = t2 + dpp_xor2(t2);
                pr2[s] = keep ? t2 : pr2[s];
                a2 = fmaf(xf.z, wtv, a2);

                float p3 = fmaxf(a3, 0.f) * w;
                float t3 = p3 + dpp_xor1(p3); t3 = t3 + dpp_xor2(t3);
                pr3[s] = keep ? t3 : pr3[s];
                a3 = fmaf(xf.w, wtv, a3);
            }

            // cross-quad reduce within the wave
            #pragma unroll
            for (int s = 0; s < 8; ++s) {
                float v;
                v = pr0[s];
                v += __shfl_xor(v, 4, 64); v += __shfl_xor(v, 8, 64);
                v += __shfl_xor(v, 16, 64); v += __shfl_xor(v, 32, 64);
                pr0[s] = v;
                v = pr1[s];
                v += __shfl_xor(v, 4, 64); v += __shfl_xor(v, 8, 64);
                v += __shfl_xor(v, 16, 64); v += __shfl_xor(v, 32, 64);
                pr1[s] = v;
                v = pr2[s];
                v += __shfl_xor(v, 4, 64); v += __shfl_xor(v, 8, 64);
                v += __shfl_xor(v, 16, 64); v += __shfl_xor(v, 32, 64);
                pr2[s] = v;
                v = pr3[s];
                v += __shfl_xor(v, 4, 64); v += __shfl_xor(v, 8, 64);
                v += __shfl_xor(v, 16, 64); v += __shfl_xor(v, 32, 64);
                pr3[s] = v;
            }

            if (lane < 4) {
                #pragma unroll
                for (int s = 0; s < 8; ++s) {
                    red[wv][0][s * 4 + lane] = pr0[s];
                    red[wv][1][s * 4 + lane] = pr1[s];
                    red[wv][2][s * 4 + lane] = pr2[s];
                    red[wv][3][s * 4 + lane] = pr3[s];
                }
            }
            __syncthreads();

            if (tid < BG * L) {
                int b = tid >> 5;
                int il = tid & 31;
                float t = red[0][b][il] + red[1][b][il] + red[2][b][il] + red[3][b][il];
                Q[((size_t)hq * B + (b0 + b)) * D + c * L + il] = t;
            }
        }
    }
    grid.sync();

    // ---------------- Phase 3: combine quarters + bias + sigmoid ------------
    for (int idx = bid * 256 + tid; idx < B * D; idx += ngrid * 256) {
        int d = idx & (D - 1);
        float t = Q[idx] + Q[(size_t)B * D + idx] + Q[2 * (size_t)B * D + idx]
                + Q[3 * (size_t)B * D + idx] + h_b[d];
        out[idx] = 1.0f / (1.0f + expf(-t));
    }
}

// ===========================================================================
// Fallback path: R6's verified 5 kernels (41.2 us, absmax 0.0)
// ===========================================================================
__global__ void k_transpose(const float* __restrict__ in, float* __restrict__ out) {
    __shared__ float tile[32][33];
    int bx = blockIdx.x * 32;
    int by = blockIdx.y * 32;
    int tx = threadIdx.x;
    int ty = threadIdx.y;
    #pragma unroll
    for (int r = 0; r < 32; r += 8)
        tile[ty + r][tx] = in[(by + ty + r) * D + (bx + tx)];
    __syncthreads();
    #pragma unroll
    for (int r = 0; r < 32; r += 8)
        out[(bx + ty + r) * H + (by + tx)] = tile[tx][ty + r];
}

__global__ void __launch_bounds__(256)
k_chunk_sums(const float* __restrict__ x,
             const float* __restrict__ Wt,
             float* __restrict__ S) {
    int blk = blockIdx.x;
    int bg  = blk >> 7;
    int chq = blk & 127;
    int c   = chq >> 2;
    int hq  = chq & 3;
    int b0  = bg * BG;
    int tid = threadIdx.x;
    int h   = hq * HP + tid;

    __shared__ float4 xs4[L];
    if (tid < L) {
        int i = c * L + tid;
        xs4[tid] = make_float4(x[(size_t)b0 * D + i],
                               x[(size_t)(b0 + 1) * D + i],
                               x[(size_t)(b0 + 2) * D + i],
                               x[(size_t)(b0 + 3) * D + i]);
    }
    __syncthreads();

    float acc0 = 0.f, acc1 = 0.f, acc2 = 0.f, acc3 = 0.f;
    #pragma unroll
    for (int j = 0; j < L; ++j) {
        float w = Wt[(size_t)(c * L + j) * H + h];
        float4 xf = xs4[j];
        acc0 = fmaf(xf.x, w, acc0);
        acc1 = fmaf(xf.y, w, acc1);
        acc2 = fmaf(xf.z, w, acc2);
        acc3 = fmaf(xf.w, w, acc3);
    }
    S[((size_t)b0 * C + c) * H + h]       = acc0;
    S[((size_t)(b0 + 1) * C + c) * H + h] = acc1;
    S[((size_t)(b0 + 2) * C + c) * H + h] = acc2;
    S[((size_t)(b0 + 3) * C + c) * H + h] = acc3;
}

__global__ void k_scan(float* __restrict__ S) {
    int tid = blockIdx.x * blockDim.x + threadIdx.x;
    if (tid >= B * H) return;
    int b = tid / H;
    int h = tid % H;
    float run = 0.f;
    #pragma unroll
    for (int c = 0; c < C; ++c) {
        int idx = (b * C + c) * H + h;
        float v = S[idx];
        S[idx] = run;
        run += v;
    }
}

__global__ void __launch_bounds__(256)
k_nade_main(const float* __restrict__ x,
            const float* __restrict__ Wt,
            const float* __restrict__ in_b,
            const float* __restrict__ h_W,
            const float* __restrict__ P,
            float* __restrict__ Q) {
    int blk = blockIdx.x;
    int bg  = blk >> 7;
    int chq = blk & 127;
    int c   = chq >> 2;
    int hq  = chq & 3;
    int b0  = bg * BG;
    int tid = threadIdx.x;
    int h   = hq * HP + tid;
    int lane = tid & 63;
    int wv = tid >> 6;
    int ph = lane & 3;

    __shared__ float4 xs4[L];
    __shared__ float red[4][BG][L];
    if (tid < L) {
        int i = c * L + tid;
        xs4[tid] = make_float4(x[(size_t)b0 * D + i],
                               x[(size_t)(b0 + 1) * D + i],
                               x[(size_t)(b0 + 2) * D + i],
                               x[(size_t)(b0 + 3) * D + i]);
    }

    float ib = in_b[h];
    float a0 = P[((size_t)b0 * C + c) * H + h] + ib;
    float a1 = P[((size_t)(b0 + 1) * C + c) * H + h] + ib;
    float a2 = P[((size_t)(b0 + 2) * C + c) * H + h] + ib;
    float a3 = P[((size_t)(b0 + 3) * C + c) * H + h] + ib;

    __syncthreads();

    bool k0 = (ph == 0), k1 = (ph == 1), k2 = (ph == 2), k3 = (ph == 3);

    float pr0[8], pr1[8], pr2[8], pr3[8];
    #pragma unroll
    for (int s = 0; s < 8; ++s) { pr0[s] = 0.f; pr1[s] = 0.f; pr2[s] = 0.f; pr3[s] = 0.f; }

    #pragma unroll
    for (int il = 0; il < L; ++il) {
        int i = c * L + il;
        float w  = h_W[(size_t)i * H + h];
        float wt = Wt[(size_t)i * H + h];
        float4 xf = xs4[il];
        int s = il >> 2;
        bool keep = (il & 3) == 0 ? k0 : ((il & 3) == 1 ? k1 : ((il & 3) == 2 ? k2 : k3));

        float p0 = fmaxf(a0, 0.f) * w;
        float t0 = p0 + dpp_xor1(p0); t0 = t0 + dpp_xor2(t0);
        pr0[s] = keep ? t0 : pr0[s];
        a0 = fmaf(xf.x, wt, a0);

        float p1 = fmaxf(a1, 0.f) * w;
        float t1 = p1 + dpp_xor1(p1); t1 = t1 + dpp_xor2(t1);
        pr1[s] = keep ? t1 : pr1[s];
        a1 = fmaf(xf.y, wt, a1);

        float p2 = fmaxf(a2, 0.f) * w;
        float t2 = p2 + dpp_xor1(p2); t2 = t2 + dpp_xor2(t2);
        pr2[s] = keep ? t2 : pr2[s];
        a2 = fmaf(xf.z, wt, a2);

        float p3 = fmaxf(a3, 0.f) * w;
        float t3 = p3 + dpp_xor1(p3); t3 = t3 + dpp_xor2(t3);
        pr3[s] = keep ? t3 : pr3[s];
        a3 = fmaf(xf.w, wt, a3);
    }

    #pragma unroll
    for (int s = 0; s < 8; ++s) {
        float v;
        v = pr0[s];
        v += __shfl_xor(v, 4, 64); v += __shfl_xor(v, 8, 64);
        v += __shfl_xor(v, 16, 64); v += __shfl_xor(v, 32, 64);
        pr0[s] = v;
        v = pr1[s];
        v += __shfl_xor(v, 4, 64); v += __shfl_xor(v, 8, 64);
        v += __shfl_xor(v, 16, 64); v += __shfl_xor(v, 32, 64);
        pr1[s] = v;
        v = pr2[s];
        v += __shfl_xor(v, 4, 64); v += __shfl_xor(v, 8, 64);
        v += __shfl_xor(v, 16, 64); v += __shfl_xor(v, 32, 64);
        pr2[s] = v;
        v = pr3[s];
        v += __shfl_xor(v, 4, 64); v += __shfl_xor(v, 8, 64);
        v += __shfl_xor(v, 16, 64); v += __shfl_xor(v, 32, 64);
        pr3[s] = v;
    }

    if (lane < 4) {
        #pragma unroll
        for (int s = 0; s < 8; ++s) {
            red[wv][0][s * 4 + lane] = pr0[s];
            red[wv][1][s * 4 + lane] = pr1[s];
            red[wv][2][s * 4 + lane] = pr2[s];
            red[wv][3][s * 4 + lane] = pr3[s];
        }
    }
    __syncthreads();

    if (tid < BG * L) {
        int b = tid >> 5;
        int il = tid & 31;
        float t = red[0][b][il] + red[1][b][il] + red[2][b][il] + red[3][b][il];
        Q[((size_t)hq * B + (b0 + b)) * D + c * L + il] = t;
    }
}

__global__ void __launch_bounds__(256)
k_combine(const float* __restrict__ Q,
          const float* __restrict__ h_b,
          float* __restrict__ out) {
    int idx = blockIdx.x * blockDim.x + threadIdx.x;
    if (idx >= B * D) return;
    int d = idx & (D - 1);
    float t = Q[idx] + Q[(size_t)B * D + idx] + Q[2 * (size_t)B * D + idx]
            + Q[3 * (size_t)B * D + idx] + h_b[d];
    out[idx] = 1.0f / (1.0f + expf(-t));
}

// ---------------------------------------------------------------------------
extern "C" void kernel_launch(void* const* d_in, const int* in_sizes, int n_in,
                              void* d_out, int out_size, void* d_ws, size_t ws_size,
                              hipStream_t stream) {
    const float* x    = (const float*)d_in[0];  // [B, D]
    const float* in_W = (const float*)d_in[1];  // [H, D]
    const float* in_b = (const float*)d_in[2];  // [H]
    const float* h_W  = (const float*)d_in[3];  // [D, H]
    const float* h_b  = (const float*)d_in[4];  // [D]
    float* out = (float*)d_out;                 // [B, D]

    float* Wt = (float*)d_ws;                   // [D, H]      4 MB
    float* S  = Wt + (size_t)D * H;             // [B, C, H]   8 MB
    float* Q  = S + (size_t)B * C * H;          // [HQ, B, D]  1 MB

    // --- Try cooperative single-kernel path (occupancy-sized grid) ---
    int maxBlocksPerCU = 0;
    hipError_t qe = hipOccupancyMaxActiveBlocksPerMultiprocessor(
        &maxBlocksPerCU, k_fused, 256, 0);
    int ngrid = 0;
    if (qe == hipSuccess && maxBlocksPerCU > 0) {
        ngrid = maxBlocksPerCU * 256;           // 256 CUs on MI355X
        if (ngrid > MAXGRID) ngrid = MAXGRID;
    }

    bool coop_ok = false;
    if (ngrid >= 256) {
        void* kargs[] = {
            (void*)&x, (void*)&in_W, (void*)&in_b, (void*)&h_W, (void*)&h_b,
            (void*)&Wt, (void*)&S, (void*)&Q, (void*)&out, (void*)&ngrid
        };
        hipError_t le = hipLaunchCooperativeKernel(
            k_fused, dim3(ngrid), dim3(256), kargs, 0, stream);
        coop_ok = (le == hipSuccess);
    }

    if (!coop_ok) {
        // --- Fallback: verified R6 5-kernel path ---
        dim3 tb(32, 8);
        dim3 tg(D / 32, H / 32);
        k_transpose<<<tg, tb, 0, stream>>>(in_W, Wt);
        k_chunk_sums<<<NBG * C * HQ, 256, 0, stream>>>(x, Wt, S);
        k_scan<<<(B * H + 255) / 256, 256, 0, stream>>>(S);
        k_nade_main<<<NBG * C * HQ, 256, 0, stream>>>(x, Wt, in_b, h_W, S, Q);
        k_combine<<<(B * D + 255) / 256, 256, 0, stream>>>(Q, h_b, out);
    }
}

// Round 11
// 43.577 us; speedup vs baseline: 7.4572x; 7.4572x over previous
//
#include <hip/hip_runtime.h>
#include <hip/hip_bf16.h>

// Problem constants
#define B 64
#define D 1024
#define H 1024
#define C 32           // chunks along D
#define L (D / C)      // chunk length = 32
#define BG 4           // batch rows per block (register-shared weight loads)
#define NBG (B / BG)   // 16 batch groups
#define HQ 4           // h-quarters
#define HP (H / HQ)    // 256 h per block = 1 h per thread

// DPP quad-perm cross-lane (VALU-speed, no LDS)
__device__ __forceinline__ float dpp_xor1(float v) {
    int i = __builtin_bit_cast(int, v);
    i = __builtin_amdgcn_mov_dpp(i, 0xB1, 0xF, 0xF, true);  // quad_perm [1,0,3,2]
    return __builtin_bit_cast(float, i);
}
__device__ __forceinline__ float dpp_xor2(float v) {
    int i = __builtin_bit_cast(int, v);
    i = __builtin_amdgcn_mov_dpp(i, 0x4E, 0xF, 0xF, true);  // quad_perm [2,3,0,1]
    return __builtin_bit_cast(float, i);
}

// ---------------------------------------------------------------------------
// Kernel 0: transpose in_W [H, D] -> Wt [D, H]   (proven R6 access pattern)
// ---------------------------------------------------------------------------
__global__ void k_transpose(const float* __restrict__ in, float* __restrict__ out) {
    __shared__ float tile[32][33];
    int bx = blockIdx.x * 32;  // d-range
    int by = blockIdx.y * 32;  // h-range
    int tx = threadIdx.x;      // 0..31
    int ty = threadIdx.y;      // 0..7
    #pragma unroll
    for (int r = 0; r < 32; r += 8)
        tile[ty + r][tx] = in[(by + ty + r) * D + (bx + tx)];
    __syncthreads();
    #pragma unroll
    for (int r = 0; r < 32; r += 8)
        out[(bx + ty + r) * H + (by + tx)] = tile[tx][ty + r];
}

// ---------------------------------------------------------------------------
// Kernel 1: per-chunk rank-1 sums. block = (bg, c, hq); thread owns one h;
// 4 batch rows share each Wt dword in registers.  (proven R6 body)
// S[b,c,h] = sum_{j in chunk c} x[b,j]*Wt[j,h]   (x exactly {0,1})
// ---------------------------------------------------------------------------
__global__ void __launch_bounds__(256)
k_chunk_sums(const float* __restrict__ x,
             const float* __restrict__ Wt,
             float* __restrict__ S) {
    int blk = blockIdx.x;
    int bg  = blk >> 7;          // /128
    int chq = blk & 127;
    int c   = chq >> 2;
    int hq  = chq & 3;
    int b0  = bg * BG;
    int tid = threadIdx.x;
    int h   = hq * HP + tid;

    __shared__ float4 xs4[L];
    if (tid < L) {
        int i = c * L + tid;
        xs4[tid] = make_float4(x[(size_t)b0 * D + i],
                               x[(size_t)(b0 + 1) * D + i],
                               x[(size_t)(b0 + 2) * D + i],
                               x[(size_t)(b0 + 3) * D + i]);
    }
    __syncthreads();

    float acc0 = 0.f, acc1 = 0.f, acc2 = 0.f, acc3 = 0.f;
    #pragma unroll
    for (int j = 0; j < L; ++j) {
        float w = Wt[(size_t)(c * L + j) * H + h];
        float4 xf = xs4[j];
        acc0 = fmaf(xf.x, w, acc0);
        acc1 = fmaf(xf.y, w, acc1);
        acc2 = fmaf(xf.z, w, acc2);
        acc3 = fmaf(xf.w, w, acc3);
    }
    S[((size_t)b0 * C + c) * H + h]       = acc0;
    S[((size_t)(b0 + 1) * C + c) * H + h] = acc1;
    S[((size_t)(b0 + 2) * C + c) * H + h] = acc2;
    S[((size_t)(b0 + 3) * C + c) * H + h] = acc3;
}

// ---------------------------------------------------------------------------
// Kernel 2: main NADE chain with FUSED exclusive prefix (no scan kernel).
// block = (bg, c, hq), c REVERSED so longest-prefix blocks launch first.
// Thread owns one h; 4 batch rows per thread; barrier-free inner loop
// (quad-DPP reduce + keeper-lane stash, predicated FMA recurrence).
// Writes per-quarter partial dots Q[hq][b][d].   (R6 body + R8-verified prefix)
// ---------------------------------------------------------------------------
__global__ void __launch_bounds__(256)
k_nade_main(const float* __restrict__ x,
            const float* __restrict__ Wt,
            const float* __restrict__ in_b,
            const float* __restrict__ h_W,
            const float* __restrict__ S,   // raw per-chunk sums [B,C,H]
            float* __restrict__ Q) {       // [HQ][B][D] partial dots
    int blk = blockIdx.x;
    int bg  = blk >> 7;
    int chq = blk & 127;
    int c   = (C - 1) - (chq >> 2);   // reversed: big-prefix blocks first
    int hq  = chq & 3;
    int b0  = bg * BG;
    int tid = threadIdx.x;
    int h   = hq * HP + tid;
    int lane = tid & 63;
    int wv = tid >> 6;
    int ph = lane & 3;

    __shared__ float4 xs4[L];
    __shared__ float red[4][BG][L];
    if (tid < L) {
        int i = c * L + tid;
        xs4[tid] = make_float4(x[(size_t)b0 * D + i],
                               x[(size_t)(b0 + 1) * D + i],
                               x[(size_t)(b0 + 2) * D + i],
                               x[(size_t)(b0 + 3) * D + i]);
    }

    // fused exclusive prefix over chunks (coalesced, 4 independent chains)
    float ib = in_b[h];
    float a0 = ib, a1 = ib, a2 = ib, a3 = ib;
    #pragma unroll 4
    for (int cc = 0; cc < c; ++cc) {
        a0 += S[((size_t)b0 * C + cc) * H + h];
        a1 += S[((size_t)(b0 + 1) * C + cc) * H + h];
        a2 += S[((size_t)(b0 + 2) * C + cc) * H + h];
        a3 += S[((size_t)(b0 + 3) * C + cc) * H + h];
    }

    __syncthreads();

    bool k0 = (ph == 0), k1 = (ph == 1), k2 = (ph == 2), k3 = (ph == 3);

    float pr0[8], pr1[8], pr2[8], pr3[8];
    #pragma unroll
    for (int s = 0; s < 8; ++s) { pr0[s] = 0.f; pr1[s] = 0.f; pr2[s] = 0.f; pr3[s] = 0.f; }

    #pragma unroll
    for (int il = 0; il < L; ++il) {
        int i = c * L + il;
        float w  = h_W[(size_t)i * H + h];
        float wt = Wt[(size_t)i * H + h];
        float4 xf = xs4[il];
        int s = il >> 2;
        bool keep = (il & 3) == 0 ? k0 : ((il & 3) == 1 ? k1 : ((il & 3) == 2 ? k2 : k3));

        float p0 = fmaxf(a0, 0.f) * w;
        float t0 = p0 + dpp_xor1(p0); t0 = t0 + dpp_xor2(t0);
        pr0[s] = keep ? t0 : pr0[s];
        a0 = fmaf(xf.x, wt, a0);

        float p1 = fmaxf(a1, 0.f) * w;
        float t1 = p1 + dpp_xor1(p1); t1 = t1 + dpp_xor2(t1);
        pr1[s] = keep ? t1 : pr1[s];
        a1 = fmaf(xf.y, wt, a1);

        float p2 = fmaxf(a2, 0.f) * w;
        float t2 = p2 + dpp_xor1(p2); t2 = t2 + dpp_xor2(t2);
        pr2[s] = keep ? t2 : pr2[s];
        a2 = fmaf(xf.z, wt, a2);

        float p3 = fmaxf(a3, 0.f) * w;
        float t3 = p3 + dpp_xor1(p3); t3 = t3 + dpp_xor2(t3);
        pr3[s] = keep ? t3 : pr3[s];
        a3 = fmaf(xf.w, wt, a3);
    }

    // cross-quad reduce within the wave (sum over 16 quads = 64 h)
    #pragma unroll
    for (int s = 0; s < 8; ++s) {
        float v;
        v = pr0[s];
        v += __shfl_xor(v, 4, 64); v += __shfl_xor(v, 8, 64);
        v += __shfl_xor(v, 16, 64); v += __shfl_xor(v, 32, 64);
        pr0[s] = v;
        v = pr1[s];
        v += __shfl_xor(v, 4, 64); v += __shfl_xor(v, 8, 64);
        v += __shfl_xor(v, 16, 64); v += __shfl_xor(v, 32, 64);
        pr1[s] = v;
        v = pr2[s];
        v += __shfl_xor(v, 4, 64); v += __shfl_xor(v, 8, 64);
        v += __shfl_xor(v, 16, 64); v += __shfl_xor(v, 32, 64);
        pr2[s] = v;
        v = pr3[s];
        v += __shfl_xor(v, 4, 64); v += __shfl_xor(v, 8, 64);
        v += __shfl_xor(v, 16, 64); v += __shfl_xor(v, 32, 64);
        pr3[s] = v;
    }

    if (lane < 4) {
        #pragma unroll
        for (int s = 0; s < 8; ++s) {
            red[wv][0][s * 4 + lane] = pr0[s];
            red[wv][1][s * 4 + lane] = pr1[s];
            red[wv][2][s * 4 + lane] = pr2[s];
            red[wv][3][s * 4 + lane] = pr3[s];
        }
    }
    __syncthreads();

    if (tid < BG * L) {
        int b = tid >> 5;
        int il = tid & 31;
        float t = red[0][b][il] + red[1][b][il] + red[2][b][il] + red[3][b][il];
        Q[((size_t)hq * B + (b0 + b)) * D + c * L + il] = t;
    }
}

// ---------------------------------------------------------------------------
// Kernel 3: combine h-quarter partials + bias + sigmoid
// ---------------------------------------------------------------------------
__global__ void __launch_bounds__(256)
k_combine(const float* __restrict__ Q,
          const float* __restrict__ h_b,
          float* __restrict__ out) {
    int idx = blockIdx.x * blockDim.x + threadIdx.x;  // 0 .. B*D-1
    if (idx >= B * D) return;
    int d = idx & (D - 1);
    float t = Q[idx] + Q[(size_t)B * D + idx] + Q[2 * (size_t)B * D + idx]
            + Q[3 * (size_t)B * D + idx] + h_b[d];
    out[idx] = 1.0f / (1.0f + expf(-t));
}

// ---------------------------------------------------------------------------
extern "C" void kernel_launch(void* const* d_in, const int* in_sizes, int n_in,
                              void* d_out, int out_size, void* d_ws, size_t ws_size,
                              hipStream_t stream) {
    const float* x    = (const float*)d_in[0];  // [B, D]
    const float* in_W = (const float*)d_in[1];  // [H, D]
    const float* in_b = (const float*)d_in[2];  // [H]
    const float* h_W  = (const float*)d_in[3];  // [D, H]
    const float* h_b  = (const float*)d_in[4];  // [D]
    float* out = (float*)d_out;                 // [B, D]

    float* Wt = (float*)d_ws;                   // [D, H]      4 MB
    float* S  = Wt + (size_t)D * H;             // [B, C, H]   8 MB
    float* Q  = S + (size_t)B * C * H;          // [HQ, B, D]  1 MB

    // 0: transpose in_W -> Wt
    dim3 tb(32, 8);
    dim3 tg(D / 32, H / 32);
    k_transpose<<<tg, tb, 0, stream>>>(in_W, Wt);

    // 1: chunk sums (BG=4 register reuse, h-quarter split)
    k_chunk_sums<<<NBG * C * HQ, 256, 0, stream>>>(x, Wt, S);

    // 2: main serial chain (fused exclusive prefix, reversed-c launch order)
    k_nade_main<<<NBG * C * HQ, 256, 0, stream>>>(x, Wt, in_b, h_W, S, Q);

    // 3: combine quarters + sigmoid
    k_combine<<<(B * D + 255) / 256, 256, 0, stream>>>(Q, h_b, out);
}

// Round 12
// 40.573 us; speedup vs baseline: 8.0094x; 1.0740x over previous
//
#include <hip/hip_runtime.h>
#include <hip/hip_bf16.h>

// Problem constants
#define B 64
#define D 1024
#define H 1024
#define C 32           // chunks along D
#define L (D / C)      // chunk length = 32
#define BG 4           // batch rows per block (register-shared weight loads)
#define NBG (B / BG)   // 16 batch groups
#define HQ 4           // h-quarters
#define HP (H / HQ)    // 256 h per block = 1 h per thread

// DPP quad-perm cross-lane (VALU-speed, no LDS)
__device__ __forceinline__ float dpp_xor1(float v) {
    int i = __builtin_bit_cast(int, v);
    i = __builtin_amdgcn_mov_dpp(i, 0xB1, 0xF, 0xF, true);  // quad_perm [1,0,3,2]
    return __builtin_bit_cast(float, i);
}
__device__ __forceinline__ float dpp_xor2(float v) {
    int i = __builtin_bit_cast(int, v);
    i = __builtin_amdgcn_mov_dpp(i, 0x4E, 0xF, 0xF, true);  // quad_perm [2,3,0,1]
    return __builtin_bit_cast(float, i);
}

// round-to-nearest-even f32 -> bf16 bits (low 16)
__device__ __forceinline__ unsigned bf16r(float f) {
    unsigned u = __builtin_bit_cast(unsigned, f);
    return (u + 0x7FFFu + ((u >> 16) & 1u)) >> 16;
}

// ---------------------------------------------------------------------------
// Kernel 0: pack PK[d][h] = bf16(h_W[d,h])<<16 | bf16(in_W[h,d])
// (transpose of in_W via LDS tile, h_W read coalesced; same cost as the old
//  transpose kernel)
// ---------------------------------------------------------------------------
__global__ void k_pack(const float* __restrict__ in_W,
                       const float* __restrict__ h_W,
                       unsigned* __restrict__ PK) {
    __shared__ float tile[32][33];
    int bx = blockIdx.x * 32;  // d-range
    int by = blockIdx.y * 32;  // h-range
    int tx = threadIdx.x;      // 0..31
    int ty = threadIdx.y;      // 0..7
    #pragma unroll
    for (int r = 0; r < 32; r += 8)
        tile[ty + r][tx] = in_W[(size_t)(by + ty + r) * D + (bx + tx)];
    __syncthreads();
    #pragma unroll
    for (int r = 0; r < 32; r += 8) {
        int d = bx + ty + r;
        int h = by + tx;
        float hw = h_W[(size_t)d * H + h];       // coalesced in tx
        float iw = tile[tx][ty + r];             // in_W[h][d]
        PK[(size_t)d * H + h] = (bf16r(hw) << 16) | bf16r(iw);
    }
}

// ---------------------------------------------------------------------------
// Kernel 1: per-chunk rank-1 sums. block = (bg, c, hq); thread owns one h;
// 4 batch rows share each packed weight dword in registers.
// S[b,c,h] = sum_{j in chunk c} x[b,j]*in_W[h,j]   (x exactly {0,1})
// ---------------------------------------------------------------------------
__global__ void __launch_bounds__(256)
k_chunk_sums(const float* __restrict__ x,
             const unsigned* __restrict__ PK,
             float* __restrict__ S) {
    int blk = blockIdx.x;
    int bg  = blk >> 7;          // /128
    int chq = blk & 127;
    int c   = chq >> 2;
    int hq  = chq & 3;
    int b0  = bg * BG;
    int tid = threadIdx.x;
    int h   = hq * HP + tid;

    __shared__ float4 xs4[L];
    if (tid < L) {
        int i = c * L + tid;
        xs4[tid] = make_float4(x[(size_t)b0 * D + i],
                               x[(size_t)(b0 + 1) * D + i],
                               x[(size_t)(b0 + 2) * D + i],
                               x[(size_t)(b0 + 3) * D + i]);
    }
    __syncthreads();

    float acc0 = 0.f, acc1 = 0.f, acc2 = 0.f, acc3 = 0.f;
    #pragma unroll
    for (int j = 0; j < L; ++j) {
        unsigned pk = PK[(size_t)(c * L + j) * H + h];
        float w = __builtin_bit_cast(float, pk << 16);   // in_W[h, cL+j]
        float4 xf = xs4[j];
        acc0 = fmaf(xf.x, w, acc0);
        acc1 = fmaf(xf.y, w, acc1);
        acc2 = fmaf(xf.z, w, acc2);
        acc3 = fmaf(xf.w, w, acc3);
    }
    S[((size_t)b0 * C + c) * H + h]       = acc0;
    S[((size_t)(b0 + 1) * C + c) * H + h] = acc1;
    S[((size_t)(b0 + 2) * C + c) * H + h] = acc2;
    S[((size_t)(b0 + 3) * C + c) * H + h] = acc3;
}

// ---------------------------------------------------------------------------
// Kernel 2: in-place exclusive scan over chunks (cheap, one-time; R11 proved
// fusing this into main costs MORE in redundant S traffic)
// ---------------------------------------------------------------------------
__global__ void k_scan(float* __restrict__ S) {
    int tid = blockIdx.x * blockDim.x + threadIdx.x;  // 0 .. B*H-1
    if (tid >= B * H) return;
    int b = tid / H;
    int h = tid % H;
    float run = 0.f;
    #pragma unroll
    for (int c = 0; c < C; ++c) {
        int idx = (b * C + c) * H + h;
        float v = S[idx];
        S[idx] = run;
        run += v;
    }
}

// ---------------------------------------------------------------------------
// Kernel 3: main NADE chain. block = (bg, c, hq); thread owns one h;
// 4 batch rows per thread. ONE packed weight load per iteration (was two):
// w = pk & 0xFFFF0000 (h_W), wt = pk << 16 (in_W). Barrier-free inner loop,
// quad-DPP reduce + keeper-lane stash, predicated FMA recurrence.
// Writes per-quarter partial dots Q[hq][b][d].
// ---------------------------------------------------------------------------
__global__ void __launch_bounds__(256)
k_nade_main(const float* __restrict__ x,
            const unsigned* __restrict__ PK,
            const float* __restrict__ in_b,
            const float* __restrict__ P,   // exclusive chunk prefixes [B,C,H]
            float* __restrict__ Q) {       // [HQ][B][D] partial dots
    int blk = blockIdx.x;
    int bg  = blk >> 7;
    int chq = blk & 127;
    int c   = chq >> 2;
    int hq  = chq & 3;
    int b0  = bg * BG;
    int tid = threadIdx.x;
    int h   = hq * HP + tid;
    int lane = tid & 63;
    int wv = tid >> 6;
    int ph = lane & 3;

    __shared__ float4 xs4[L];
    __shared__ float red[4][BG][L];
    if (tid < L) {
        int i = c * L + tid;
        xs4[tid] = make_float4(x[(size_t)b0 * D + i],
                               x[(size_t)(b0 + 1) * D + i],
                               x[(size_t)(b0 + 2) * D + i],
                               x[(size_t)(b0 + 3) * D + i]);
    }

    float ib = in_b[h];
    float a0 = P[((size_t)b0 * C + c) * H + h] + ib;
    float a1 = P[((size_t)(b0 + 1) * C + c) * H + h] + ib;
    float a2 = P[((size_t)(b0 + 2) * C + c) * H + h] + ib;
    float a3 = P[((size_t)(b0 + 3) * C + c) * H + h] + ib;

    __syncthreads();

    bool k0 = (ph == 0), k1 = (ph == 1), k2 = (ph == 2), k3 = (ph == 3);

    float pr0[8], pr1[8], pr2[8], pr3[8];
    #pragma unroll
    for (int s = 0; s < 8; ++s) { pr0[s] = 0.f; pr1[s] = 0.f; pr2[s] = 0.f; pr3[s] = 0.f; }

    #pragma unroll
    for (int il = 0; il < L; ++il) {
        int i = c * L + il;
        unsigned pk = PK[(size_t)i * H + h];
        float w  = __builtin_bit_cast(float, pk & 0xFFFF0000u);  // h_W[i,h]
        float wt = __builtin_bit_cast(float, pk << 16);          // in_W[h,i]
        float4 xf = xs4[il];
        int s = il >> 2;
        bool keep = (il & 3) == 0 ? k0 : ((il & 3) == 1 ? k1 : ((il & 3) == 2 ? k2 : k3));

        float p0 = fmaxf(a0, 0.f) * w;
        float t0 = p0 + dpp_xor1(p0); t0 = t0 + dpp_xor2(t0);
        pr0[s] = keep ? t0 : pr0[s];
        a0 = fmaf(xf.x, wt, a0);

        float p1 = fmaxf(a1, 0.f) * w;
        float t1 = p1 + dpp_xor1(p1); t1 = t1 + dpp_xor2(t1);
        pr1[s] = keep ? t1 : pr1[s];
        a1 = fmaf(xf.y, wt, a1);

        float p2 = fmaxf(a2, 0.f) * w;
        float t2 = p2 + dpp_xor1(p2); t2 = t2 + dpp_xor2(t2);
        pr2[s] = keep ? t2 : pr2[s];
        a2 = fmaf(xf.z, wt, a2);

        float p3 = fmaxf(a3, 0.f) * w;
        float t3 = p3 + dpp_xor1(p3); t3 = t3 + dpp_xor2(t3);
        pr3[s] = keep ? t3 : pr3[s];
        a3 = fmaf(xf.w, wt, a3);
    }

    // cross-quad reduce within the wave (sum over 16 quads = 64 h)
    #pragma unroll
    for (int s = 0; s < 8; ++s) {
        float v;
        v = pr0[s];
        v += __shfl_xor(v, 4, 64); v += __shfl_xor(v, 8, 64);
        v += __shfl_xor(v, 16, 64); v += __shfl_xor(v, 32, 64);
        pr0[s] = v;
        v = pr1[s];
        v += __shfl_xor(v, 4, 64); v += __shfl_xor(v, 8, 64);
        v += __shfl_xor(v, 16, 64); v += __shfl_xor(v, 32, 64);
        pr1[s] = v;
        v = pr2[s];
        v += __shfl_xor(v, 4, 64); v += __shfl_xor(v, 8, 64);
        v += __shfl_xor(v, 16, 64); v += __shfl_xor(v, 32, 64);
        pr2[s] = v;
        v = pr3[s];
        v += __shfl_xor(v, 4, 64); v += __shfl_xor(v, 8, 64);
        v += __shfl_xor(v, 16, 64); v += __shfl_xor(v, 32, 64);
        pr3[s] = v;
    }

    if (lane < 4) {
        #pragma unroll
        for (int s = 0; s < 8; ++s) {
            red[wv][0][s * 4 + lane] = pr0[s];
            red[wv][1][s * 4 + lane] = pr1[s];
            red[wv][2][s * 4 + lane] = pr2[s];
            red[wv][3][s * 4 + lane] = pr3[s];
        }
    }
    __syncthreads();

    if (tid < BG * L) {
        int b = tid >> 5;
        int il = tid & 31;
        float t = red[0][b][il] + red[1][b][il] + red[2][b][il] + red[3][b][il];
        Q[((size_t)hq * B + (b0 + b)) * D + c * L + il] = t;
    }
}

// ---------------------------------------------------------------------------
// Kernel 4: combine h-quarter partials + bias + sigmoid
// ---------------------------------------------------------------------------
__global__ void __launch_bounds__(256)
k_combine(const float* __restrict__ Q,
          const float* __restrict__ h_b,
          float* __restrict__ out) {
    int idx = blockIdx.x * blockDim.x + threadIdx.x;  // 0 .. B*D-1
    if (idx >= B * D) return;
    int d = idx & (D - 1);
    float t = Q[idx] + Q[(size_t)B * D + idx] + Q[2 * (size_t)B * D + idx]
            + Q[3 * (size_t)B * D + idx] + h_b[d];
    out[idx] = 1.0f / (1.0f + expf(-t));
}

// ---------------------------------------------------------------------------
extern "C" void kernel_launch(void* const* d_in, const int* in_sizes, int n_in,
                              void* d_out, int out_size, void* d_ws, size_t ws_size,
                              hipStream_t stream) {
    const float* x    = (const float*)d_in[0];  // [B, D]
    const float* in_W = (const float*)d_in[1];  // [H, D]
    const float* in_b = (const float*)d_in[2];  // [H]
    const float* h_W  = (const float*)d_in[3];  // [D, H]
    const float* h_b  = (const float*)d_in[4];  // [D]
    float* out = (float*)d_out;                 // [B, D]

    unsigned* PK = (unsigned*)d_ws;             // [D, H] packed   4 MB
    float* S = (float*)(PK + (size_t)D * H);    // [B, C, H]       8 MB
    float* Q = S + (size_t)B * C * H;           // [HQ, B, D]      1 MB

    // 0: pack weights (bf16 pair per dword; includes in_W transpose)
    dim3 tb(32, 8);
    dim3 tg(D / 32, H / 32);
    k_pack<<<tg, tb, 0, stream>>>(in_W, h_W, PK);

    // 1: chunk sums (packed weights, BG=4 register reuse)
    k_chunk_sums<<<NBG * C * HQ, 256, 0, stream>>>(x, PK, S);

    // 2: exclusive scan over chunks (in place)
    k_scan<<<(B * H + 255) / 256, 256, 0, stream>>>(S);

    // 3: main serial chain (single packed weight load per iteration)
    k_nade_main<<<NBG * C * HQ, 256, 0, stream>>>(x, PK, in_b, S, Q);

    // 4: combine quarters + sigmoid
    k_combine<<<(B * D + 255) / 256, 256, 0, stream>>>(Q, h_b, out);
}